// Round 1
// baseline (210.840 us; speedup 1.0000x reference)
//
#include <hip/hip_runtime.h>
#include <math.h>

#define NUM_Q_ 10000
#define NUM_A_ 10000
#define DIM 128
#define MSZ 50
#define BB 64
#define NN 200
#define RPOS 8

typedef float f4 __attribute__((ext_vector_type(4)));

// ---------------- Phase A: gather + w(softmax) + e(sigmoid) + ad(tanh) ----------------
__global__ __launch_bounds__(128) void phaseA(
    const int* __restrict__ q, const int* __restrict__ r, const int* __restrict__ a,
    const float* __restrict__ Kemb, const float* __restrict__ Vemb, const float* __restrict__ VAemb,
    const float* __restrict__ Mk, const float* __restrict__ eW, const float* __restrict__ eb,
    const float* __restrict__ aW, const float* __restrict__ ab,
    float* __restrict__ w_ws, float* __restrict__ e_ws, float* __restrict__ ad_ws)
{
    const int tid = threadIdx.x;
    const int pos0 = blockIdx.x * RPOS;
    __shared__ float s_s[RPOS][DIM];
    __shared__ float s_k[RPOS][DIM];

    #pragma unroll
    for (int p = 0; p < RPOS; ++p) {
        int pos = pos0 + p;
        int qi = q[pos], ri = r[pos], ai = a[pos];
        int xi = qi + NUM_Q_ * ri;
        int axi = ai + NUM_A_ * ri;
        s_k[p][tid] = Kemb[(size_t)qi * DIM + tid];
        s_s[p][tid] = Vemb[(size_t)xi * DIM + tid] + VAemb[(size_t)axi * DIM + tid];
    }
    __syncthreads();

    float acc_e[RPOS], acc_a[RPOS], acc_l[RPOS];
    #pragma unroll
    for (int p = 0; p < RPOS; ++p) { acc_e[p] = 0.f; acc_a[p] = 0.f; acc_l[p] = 0.f; }

    const bool hasM = (tid < MSZ);
    const f4* eWr = (const f4*)(eW + (size_t)tid * DIM);
    const f4* aWr = (const f4*)(aW + (size_t)tid * DIM);
    const f4* mkr = (const f4*)(Mk + (size_t)(hasM ? tid : 0) * DIM);

    for (int i4 = 0; i4 < DIM / 4; ++i4) {
        f4 we = eWr[i4];
        f4 wa = aWr[i4];
        #pragma unroll
        for (int c = 0; c < 4; ++c) {
            int i = i4 * 4 + c;
            #pragma unroll
            for (int p = 0; p < RPOS; ++p) {
                float sv = s_s[p][i];
                acc_e[p] = fmaf(sv, we[c], acc_e[p]);
                acc_a[p] = fmaf(sv, wa[c], acc_a[p]);
            }
        }
        if (hasM) {
            f4 mk = mkr[i4];
            #pragma unroll
            for (int c = 0; c < 4; ++c) {
                int i = i4 * 4 + c;
                #pragma unroll
                for (int p = 0; p < RPOS; ++p)
                    acc_l[p] = fmaf(s_k[p][i], mk[c], acc_l[p]);
            }
        }
    }

    // e / ad outputs (coalesced over tid)
    float ebv = eb[tid], abv = ab[tid];
    #pragma unroll
    for (int p = 0; p < RPOS; ++p) {
        float ev = 1.f / (1.f + __expf(-(acc_e[p] + ebv)));
        float av = tanhf(acc_a[p] + abv);
        e_ws[(size_t)(pos0 + p) * DIM + tid] = ev;
        ad_ws[(size_t)(pos0 + p) * DIM + tid] = av;
    }

    // softmax over m=50 within wave 0 (lanes 0..63)
    if (tid < 64) {
        #pragma unroll
        for (int p = 0; p < RPOS; ++p) {
            float lv = hasM ? acc_l[p] : -1e30f;
            float mx = lv;
            #pragma unroll
            for (int off = 32; off >= 1; off >>= 1)
                mx = fmaxf(mx, __shfl_xor(mx, off, 64));
            float ex = hasM ? __expf(lv - mx) : 0.f;
            float sm = ex;
            #pragma unroll
            for (int off = 32; off >= 1; off >>= 1)
                sm += __shfl_xor(sm, off, 64);
            if (hasM) w_ws[(size_t)(pos0 + p) * MSZ + tid] = ex / sm;
        }
    }
}

// ---------------- Phase B: the scan — Mv stream-out + reads ----------------
// Block owns (batch b, d-chunk of 32). Thread (g = tid/32, dl = tid%32) owns
// states for m in {g, g+16, g+32, g+48(valid g<2)} at column d = c*32+dl.
__global__ __launch_bounds__(512) void phaseB(
    const float* __restrict__ Mv0,
    const float* __restrict__ w_ws, const float* __restrict__ e_ws, const float* __restrict__ ad_ws,
    float* __restrict__ reads_ws, float* __restrict__ Mv)
{
    // XCD-aware swizzle: keep all 4 chunks of a batch on one XCD's L2.
    int bid = blockIdx.x;
    int xcd = bid & 7, idx = bid >> 3;          // idx in [0,32)
    int b = xcd * 8 + (idx >> 2);
    int c = idx & 3;

    const int tid = threadIdx.x;
    const int g = tid >> 5, dl = tid & 31;
    const int d = c * 32 + dl;
    const int m0 = g, m1 = g + 16, m2 = g + 32, m3 = g + 48;
    const bool v3 = (g < 2);                    // wave-uniform

    float M0 = Mv0[m0 * DIM + d];
    float M1 = Mv0[m1 * DIM + d];
    float M2 = Mv0[m2 * DIM + d];
    float M3 = v3 ? Mv0[m3 * DIM + d] : 0.f;

    float* MvB = Mv + (size_t)b * (NN + 1) * MSZ * DIM;
    MvB[m0 * DIM + d] = M0;
    MvB[m1 * DIM + d] = M1;
    MvB[m2 * DIM + d] = M2;
    if (v3) MvB[m3 * DIM + d] = M3;

    __shared__ float red[2][512];

    const float* wr = w_ws + (size_t)b * NN * MSZ;
    const float* er = e_ws + (size_t)b * NN * DIM + d;
    const float* ar = ad_ws + (size_t)b * NN * DIM + d;
    float* rr = reads_ws + (size_t)b * NN * DIM + c * 32;
    float* out = MvB + MSZ * DIM;

    for (int t = 0; t < NN; ++t) {
        float w0 = wr[m0], w1 = wr[m1], w2 = wr[m2];
        float w3 = v3 ? wr[m3] : 0.f;
        float ev = *er, av = *ar;

        // read from PRE-update memory
        float pr = M0 * w0 + M1 * w1 + M2 * w2 + M3 * w3;
        red[t & 1][tid] = pr;
        __syncthreads();
        if (tid < 32) {
            float s = 0.f;
            #pragma unroll
            for (int g2 = 0; g2 < 16; ++g2) s += red[t & 1][g2 * 32 + tid];
            rr[tid] = s;
        }

        // update + stream out
        M0 = M0 * (1.f - w0 * ev) + w0 * av;
        M1 = M1 * (1.f - w1 * ev) + w1 * av;
        M2 = M2 * (1.f - w2 * ev) + w2 * av;
        M3 = M3 * (1.f - w3 * ev) + w3 * av;
        out[m0 * DIM + d] = M0;
        out[m1 * DIM + d] = M1;
        out[m2 * DIM + d] = M2;
        if (v3) out[m3 * DIM + d] = M3;

        wr += MSZ; er += DIM; ar += DIM; rr += DIM; out += MSZ * DIM;
    }
}

// ---------------- Phase C: f = tanh([reads,k]@fW^T+fb), p = sigmoid(f@pW+pb) ----------------
__global__ __launch_bounds__(128) void phaseC(
    const int* __restrict__ q, const float* __restrict__ Kemb,
    const float* __restrict__ reads_ws,
    const float* __restrict__ fW, const float* __restrict__ fb,
    const float* __restrict__ pW, const float* __restrict__ pb,
    float* __restrict__ p_out)
{
    const int tid = threadIdx.x;
    const int pos0 = blockIdx.x * RPOS;
    __shared__ float s_cat[RPOS][2 * DIM];
    __shared__ float part[2][RPOS];

    #pragma unroll
    for (int p = 0; p < RPOS; ++p) {
        int pos = pos0 + p;
        s_cat[p][tid] = reads_ws[(size_t)pos * DIM + tid];
        s_cat[p][DIM + tid] = Kemb[(size_t)q[pos] * DIM + tid];
    }
    __syncthreads();

    float acc[RPOS];
    #pragma unroll
    for (int p = 0; p < RPOS; ++p) acc[p] = 0.f;

    const f4* fWr = (const f4*)(fW + (size_t)tid * 2 * DIM);
    for (int i4 = 0; i4 < (2 * DIM) / 4; ++i4) {
        f4 wf = fWr[i4];
        #pragma unroll
        for (int c = 0; c < 4; ++c) {
            int i = i4 * 4 + c;
            #pragma unroll
            for (int p = 0; p < RPOS; ++p)
                acc[p] = fmaf(s_cat[p][i], wf[c], acc[p]);
        }
    }

    float fbv = fb[tid], pwv = pW[tid];
    const int wv = tid >> 6, ln = tid & 63;
    #pragma unroll
    for (int p = 0; p < RPOS; ++p) {
        float v = tanhf(acc[p] + fbv) * pwv;
        #pragma unroll
        for (int off = 32; off >= 1; off >>= 1)
            v += __shfl_xor(v, off, 64);
        if (ln == 0) part[wv][p] = v;
    }
    __syncthreads();
    if (tid < RPOS) {
        float pv = part[0][tid] + part[1][tid] + pb[0];
        p_out[pos0 + tid] = 1.f / (1.f + __expf(-pv));
    }
}

extern "C" void kernel_launch(void* const* d_in, const int* in_sizes, int n_in,
                              void* d_out, int out_size, void* d_ws, size_t ws_size,
                              hipStream_t stream) {
    const int*   q     = (const int*)d_in[0];
    const int*   r     = (const int*)d_in[1];
    const int*   a     = (const int*)d_in[2];
    const float* Kemb  = (const float*)d_in[3];
    const float* Vemb  = (const float*)d_in[4];
    const float* VAemb = (const float*)d_in[5];
    const float* Mk    = (const float*)d_in[6];
    const float* Mv0   = (const float*)d_in[7];
    const float* fW    = (const float*)d_in[8];
    const float* fb    = (const float*)d_in[9];
    const float* pW    = (const float*)d_in[10];
    const float* pb    = (const float*)d_in[11];
    const float* eW    = (const float*)d_in[12];
    const float* eb    = (const float*)d_in[13];
    const float* aW    = (const float*)d_in[14];
    const float* ab    = (const float*)d_in[15];

    float* p_out = (float*)d_out;
    float* Mv    = p_out + BB * NN;     // p is [B,N]=12800 floats; Mv follows

    float* ws       = (float*)d_ws;
    float* w_ws     = ws;                                   // B*N*50
    float* e_ws     = w_ws + (size_t)BB * NN * MSZ;         // B*N*128
    float* ad_ws    = e_ws + (size_t)BB * NN * DIM;         // B*N*128
    float* reads_ws = ad_ws + (size_t)BB * NN * DIM;        // B*N*128

    phaseA<<<BB * NN / RPOS, 128, 0, stream>>>(q, r, a, Kemb, Vemb, VAemb,
                                               Mk, eW, eb, aW, ab,
                                               w_ws, e_ws, ad_ws);
    phaseB<<<BB * 4, 512, 0, stream>>>(Mv0, w_ws, e_ws, ad_ws, reads_ws, Mv);
    phaseC<<<BB * NN / RPOS, 128, 0, stream>>>(q, Kemb, reads_ws, fW, fb, pW, pb, p_out);
}

// Round 2
// 180.067 us; speedup vs baseline: 1.1709x; 1.1709x over previous
//
#include <hip/hip_runtime.h>
#include <math.h>

#define NUM_Q_ 10000
#define NUM_A_ 10000
#define DIM 128
#define MSZ 50
#define BB 64
#define NN 200
#define RPOS 8
#define CH 25

typedef float f4 __attribute__((ext_vector_type(4)));

// ---------------- Phase A: gather + w(softmax) + e(sigmoid) + ad(tanh) ----------------
__global__ __launch_bounds__(128) void phaseA(
    const int* __restrict__ q, const int* __restrict__ r, const int* __restrict__ a,
    const float* __restrict__ Kemb, const float* __restrict__ Vemb, const float* __restrict__ VAemb,
    const float* __restrict__ Mk, const float* __restrict__ eW, const float* __restrict__ eb,
    const float* __restrict__ aW, const float* __restrict__ ab,
    float* __restrict__ w_ws, float* __restrict__ e_ws, float* __restrict__ ad_ws)
{
    const int tid = threadIdx.x;
    const int pos0 = blockIdx.x * RPOS;
    __shared__ float s_s[RPOS][DIM];
    __shared__ float s_k[RPOS][DIM];

    #pragma unroll
    for (int p = 0; p < RPOS; ++p) {
        int pos = pos0 + p;
        int qi = q[pos], ri = r[pos], ai = a[pos];
        int xi = qi + NUM_Q_ * ri;
        int axi = ai + NUM_A_ * ri;
        s_k[p][tid] = Kemb[(size_t)qi * DIM + tid];
        s_s[p][tid] = Vemb[(size_t)xi * DIM + tid] + VAemb[(size_t)axi * DIM + tid];
    }
    __syncthreads();

    float acc_e[RPOS], acc_a[RPOS], acc_l[RPOS];
    #pragma unroll
    for (int p = 0; p < RPOS; ++p) { acc_e[p] = 0.f; acc_a[p] = 0.f; acc_l[p] = 0.f; }

    const bool hasM = (tid < MSZ);
    const f4* eWr = (const f4*)(eW + (size_t)tid * DIM);
    const f4* aWr = (const f4*)(aW + (size_t)tid * DIM);
    const f4* mkr = (const f4*)(Mk + (size_t)(hasM ? tid : 0) * DIM);

    for (int i4 = 0; i4 < DIM / 4; ++i4) {
        f4 we = eWr[i4];
        f4 wa = aWr[i4];
        #pragma unroll
        for (int c = 0; c < 4; ++c) {
            int i = i4 * 4 + c;
            #pragma unroll
            for (int p = 0; p < RPOS; ++p) {
                float sv = s_s[p][i];
                acc_e[p] = fmaf(sv, we[c], acc_e[p]);
                acc_a[p] = fmaf(sv, wa[c], acc_a[p]);
            }
        }
        if (hasM) {
            f4 mk = mkr[i4];
            #pragma unroll
            for (int c = 0; c < 4; ++c) {
                int i = i4 * 4 + c;
                #pragma unroll
                for (int p = 0; p < RPOS; ++p)
                    acc_l[p] = fmaf(s_k[p][i], mk[c], acc_l[p]);
            }
        }
    }

    float ebv = eb[tid], abv = ab[tid];
    #pragma unroll
    for (int p = 0; p < RPOS; ++p) {
        float ev = 1.f / (1.f + __expf(-(acc_e[p] + ebv)));
        float av = tanhf(acc_a[p] + abv);
        e_ws[(size_t)(pos0 + p) * DIM + tid] = ev;
        ad_ws[(size_t)(pos0 + p) * DIM + tid] = av;
    }

    if (tid < 64) {
        #pragma unroll
        for (int p = 0; p < RPOS; ++p) {
            float lv = hasM ? acc_l[p] : -1e30f;
            float mx = lv;
            #pragma unroll
            for (int off = 32; off >= 1; off >>= 1)
                mx = fmaxf(mx, __shfl_xor(mx, off, 64));
            float ex = hasM ? __expf(lv - mx) : 0.f;
            float sm = ex;
            #pragma unroll
            for (int off = 32; off >= 1; off >>= 1)
                sm += __shfl_xor(sm, off, 64);
            if (hasM) w_ws[(size_t)(pos0 + p) * MSZ + tid] = ex / sm;
        }
    }
}

// ---------------- Phase B: scan, latency-minimized ----------------
// Grid: 64 b x 4 dchunk x 2 mhalf = 512 blocks, 128 threads (2 waves).
// Wave layout: l = (lane>>4)&3 (4 lanes-groups per d), dl16 = lane&15.
// d = dchunk*32 + wave*16 + dl16. Thread owns m = h*25 + l + 4j (j<7, mloc<25).
// Steady state: LDS + registers only; reads-reduce = 2 shuffles; barriers only
// at 25-step chunk boundaries.
__global__ __launch_bounds__(128) void phaseB(
    const float* __restrict__ Mv0,
    const float* __restrict__ w_ws, const float* __restrict__ e_ws, const float* __restrict__ ad_ws,
    float* __restrict__ rp0, float* __restrict__ rp1, float* __restrict__ Mv)
{
    const int bid = blockIdx.x;
    const int h = bid & 1, dc = (bid >> 1) & 3, b = bid >> 3;
    const int tid = threadIdx.x;
    const int lane = tid & 63, wv = tid >> 6;
    const int dl16 = lane & 15, l = (lane >> 4) & 3;
    const int dloc = wv * 16 + dl16;            // 0..31
    const int d = dc * 32 + dloc;

    __shared__ float w_s[CH][25];
    __shared__ float e_s[CH][32];
    __shared__ float a_s[CH][32];

    float M[7];
    #pragma unroll
    for (int j = 0; j < 7; ++j) {
        int mloc = l + 4 * j;
        M[j] = (mloc < 25) ? Mv0[(h * 25 + mloc) * DIM + d] : 0.f;
    }

    float* MvB = Mv + (size_t)b * (NN + 1) * MSZ * DIM;
    #pragma unroll
    for (int j = 0; j < 7; ++j) {
        int mloc = l + 4 * j;
        if (mloc < 25) MvB[(h * 25 + mloc) * DIM + d] = M[j];
    }

    const float* wbase = w_ws + (size_t)b * NN * MSZ + h * 25;
    const float* ebase = e_ws + (size_t)b * NN * DIM + dc * 32;
    const float* abase = ad_ws + (size_t)b * NN * DIM + dc * 32;
    float* rbase = (h == 0 ? rp0 : rp1) + (size_t)b * NN * DIM + dc * 32;
    float* out = MvB + MSZ * DIM;               // Mv[b,1,...]

    for (int c0 = 0; c0 < NN; c0 += CH) {
        __syncthreads();
        for (int idx = tid; idx < CH * 25; idx += 128) {
            int row = idx / 25, col = idx - row * 25;
            w_s[row][col] = wbase[(size_t)(c0 + row) * MSZ + col];
        }
        for (int idx = tid; idx < CH * 32; idx += 128) {
            int row = idx >> 5, col = idx & 31;
            e_s[row][col] = ebase[(size_t)(c0 + row) * DIM + col];
            a_s[row][col] = abase[(size_t)(c0 + row) * DIM + col];
        }
        __syncthreads();

        for (int tc = 0; tc < CH; ++tc) {
            float ev = e_s[tc][dloc];
            float av = a_s[tc][dloc];
            float wj[7];
            #pragma unroll
            for (int j = 0; j < 7; ++j) {
                int mloc = l + 4 * j;
                wj[j] = (mloc < 25) ? w_s[tc][mloc] : 0.f;
            }
            float pr = 0.f;
            #pragma unroll
            for (int j = 0; j < 7; ++j) pr = fmaf(wj[j], M[j], pr);
            pr += __shfl_xor(pr, 16, 64);
            pr += __shfl_xor(pr, 32, 64);
            #pragma unroll
            for (int j = 0; j < 7; ++j) {
                float t1 = fmaf(-M[j], ev, av);       // a - M*e
                M[j] = fmaf(wj[j], t1, M[j]);         // M + w*(a - M*e)
            }
            const int t = c0 + tc;
            float* o = out + (size_t)t * MSZ * DIM;
            #pragma unroll
            for (int j = 0; j < 7; ++j) {
                int mloc = l + 4 * j;
                if (mloc < 25) o[(h * 25 + mloc) * DIM + d] = M[j];
            }
            if (l == 0) rbase[(size_t)t * DIM + dloc] = pr;
        }
    }
}

// ---------------- Phase C: f = tanh([reads,k]@fW^T+fb), p = sigmoid(f@pW+pb) ----------------
__global__ __launch_bounds__(128) void phaseC(
    const int* __restrict__ q, const float* __restrict__ Kemb,
    const float* __restrict__ rp0, const float* __restrict__ rp1,
    const float* __restrict__ fW, const float* __restrict__ fb,
    const float* __restrict__ pW, const float* __restrict__ pb,
    float* __restrict__ p_out)
{
    const int tid = threadIdx.x;
    const int pos0 = blockIdx.x * RPOS;
    __shared__ float s_cat[RPOS][2 * DIM];
    __shared__ float part[2][RPOS];

    #pragma unroll
    for (int p = 0; p < RPOS; ++p) {
        int pos = pos0 + p;
        s_cat[p][tid] = rp0[(size_t)pos * DIM + tid] + rp1[(size_t)pos * DIM + tid];
        s_cat[p][DIM + tid] = Kemb[(size_t)q[pos] * DIM + tid];
    }
    __syncthreads();

    float acc[RPOS];
    #pragma unroll
    for (int p = 0; p < RPOS; ++p) acc[p] = 0.f;

    const f4* fWr = (const f4*)(fW + (size_t)tid * 2 * DIM);
    for (int i4 = 0; i4 < (2 * DIM) / 4; ++i4) {
        f4 wf = fWr[i4];
        #pragma unroll
        for (int c = 0; c < 4; ++c) {
            int i = i4 * 4 + c;
            #pragma unroll
            for (int p = 0; p < RPOS; ++p)
                acc[p] = fmaf(s_cat[p][i], wf[c], acc[p]);
        }
    }

    float fbv = fb[tid], pwv = pW[tid];
    const int wv = tid >> 6, ln = tid & 63;
    #pragma unroll
    for (int p = 0; p < RPOS; ++p) {
        float v = tanhf(acc[p] + fbv) * pwv;
        #pragma unroll
        for (int off = 32; off >= 1; off >>= 1)
            v += __shfl_xor(v, off, 64);
        if (ln == 0) part[wv][p] = v;
    }
    __syncthreads();
    if (tid < RPOS) {
        float pv = part[0][tid] + part[1][tid] + pb[0];
        p_out[pos0 + tid] = 1.f / (1.f + __expf(-pv));
    }
}

extern "C" void kernel_launch(void* const* d_in, const int* in_sizes, int n_in,
                              void* d_out, int out_size, void* d_ws, size_t ws_size,
                              hipStream_t stream) {
    const int*   q     = (const int*)d_in[0];
    const int*   r     = (const int*)d_in[1];
    const int*   a     = (const int*)d_in[2];
    const float* Kemb  = (const float*)d_in[3];
    const float* Vemb  = (const float*)d_in[4];
    const float* VAemb = (const float*)d_in[5];
    const float* Mk    = (const float*)d_in[6];
    const float* Mv0   = (const float*)d_in[7];
    const float* fW    = (const float*)d_in[8];
    const float* fb    = (const float*)d_in[9];
    const float* pW    = (const float*)d_in[10];
    const float* pb    = (const float*)d_in[11];
    const float* eW    = (const float*)d_in[12];
    const float* eb    = (const float*)d_in[13];
    const float* aW    = (const float*)d_in[14];
    const float* ab    = (const float*)d_in[15];

    float* p_out = (float*)d_out;
    float* Mv    = p_out + BB * NN;

    float* ws    = (float*)d_ws;
    float* w_ws  = ws;                                  // B*N*50
    float* e_ws  = w_ws + (size_t)BB * NN * MSZ;        // B*N*128
    float* ad_ws = e_ws + (size_t)BB * NN * DIM;        // B*N*128
    float* rp0   = ad_ws + (size_t)BB * NN * DIM;       // B*N*128
    float* rp1   = rp0 + (size_t)BB * NN * DIM;         // B*N*128

    phaseA<<<BB * NN / RPOS, 128, 0, stream>>>(q, r, a, Kemb, Vemb, VAemb,
                                               Mk, eW, eb, aW, ab,
                                               w_ws, e_ws, ad_ws);
    phaseB<<<BB * 4 * 2, 128, 0, stream>>>(Mv0, w_ws, e_ws, ad_ws, rp0, rp1, Mv);
    phaseC<<<BB * NN / RPOS, 128, 0, stream>>>(q, Kemb, rp0, rp1, fW, fb, pW, pb, p_out);
}